// Round 8
// baseline (375.487 us; speedup 1.0000x reference)
//
#include <hip/hip_runtime.h>
#include <hip/hip_bf16.h>
#include <math.h>

#define N_NODES  50000
#define N_EDGES  800000
#define HID      128
#define OUT_DIM  40
#define N_LAYERS 4
#define N_GRAPHS 128
#define BN_EPS   1e-5f
#define TROWS    16     // rows per k_mlp block (grid 3125 -> 8 blocks/CU, 100% occ)
#define LSTRIDE  136    // LDS row stride in shorts (16B-aligned, 2-way bank alias only)
#define CAP      64     // csr bucket capacity (Poisson(16): P(deg>=64) ~ 2e-18)

typedef short v8s __attribute__((ext_vector_type(8)));
typedef float v4f __attribute__((ext_vector_type(4)));
typedef float cv4f __attribute__((ext_vector_type(4)));      // for NT loads
typedef unsigned v4u __attribute__((ext_vector_type(4)));    // for NT stores

static __device__ __forceinline__ short f2bf(float f) {
    __hip_bfloat16 h = __float2bfloat16(f);
    return __builtin_bit_cast(short, h);
}
static __device__ __forceinline__ float bflo(unsigned u) {
    return __builtin_bit_cast(float, u << 16);
}
static __device__ __forceinline__ float bfhi(unsigned u) {
    return __builtin_bit_cast(float, u & 0xffff0000u);
}
static __device__ __forceinline__ unsigned packbf(float a0, float a1) {
    return ((unsigned)(unsigned short)f2bf(a1) << 16) | (unsigned)(unsigned short)f2bf(a0);
}

// =============================================================== k_pre
// Job order matters: streaming x2b FIRST (non-temporal, won't evict csr),
// bucket fill LAST so its 6.4MB dirty set lives in a quiet L2.
//  blocks [0, 3125)     : x fp32 -> packed bf16, NT 16B loads/stores
//  blocks [3125, 3135)  : weight frag-pack (9 full mats + head W2 zero-padded)
//  blocks [3135, 3917)  : bucket fill (count+scan+fill collapsed; cursor -> degree)
__global__ __launch_bounds__(256) void k_pre(const float* __restrict__ x,
                                             unsigned* __restrict__ xb,
                                             const int* __restrict__ src,
                                             const int* __restrict__ dst,
                                             int* __restrict__ cursor,
                                             unsigned short* __restrict__ csr,
                                             const float* __restrict__ W1s,
                                             const float* __restrict__ W2s,
                                             const float* __restrict__ lin1,
                                             const float* __restrict__ lin2,
                                             short* __restrict__ Wp) {
    int b = blockIdx.x, t = threadIdx.x;
    if (b < 3125) {                                   // ---- x2b (NT 16B)
        int j = b * 256 + t;                          // 0 .. 799999
        const cv4f* x4 = (const cv4f*)x;
        cv4f f0 = __builtin_nontemporal_load(&x4[2 * j]);
        cv4f f1 = __builtin_nontemporal_load(&x4[2 * j + 1]);
        v4u o;
        o.x = packbf(f0.x, f0.y);
        o.y = packbf(f0.z, f0.w);
        o.z = packbf(f1.x, f1.y);
        o.w = packbf(f1.z, f1.w);
        __builtin_nontemporal_store(o, &((v4u*)xb)[j]);
    } else if (b < 3135) {                            // ---- weight prep
        int bp = b - 3125;
        if (bp < 9) {
            const float* W = (bp < 4) ? (W1s + bp * 16384)
                           : (bp < 8) ? (W2s + (bp - 4) * 16384)
                                      : lin1;
            short* o = Wp + (size_t)bp * 16384;
#pragma unroll
            for (int i = 0; i < 8; i++) {
                int c = i * 256 + t;                  // chunk 0..2047
                int f = c >> 6, lane = c & 63;
                int ks = f >> 3, nt = f & 7;
                int k0 = ks * 32 + (lane >> 4) * 8;
                int n  = nt * 16 + (lane & 15);
                union { v8s v; short s[8]; } u;
#pragma unroll
                for (int j = 0; j < 8; j++) u.s[j] = f2bf(W[(k0 + j) * 128 + n]);
                *(v8s*)(o + (size_t)c * 8) = u.v;
            }
        } else {                                      // head W2 [128][40] -> frags, pad->0
            short* o = Wp + (size_t)9 * 16384;
#pragma unroll
            for (int i = 0; i < 3; i++) {
                int c = i * 256 + t;
                if (c < 768) {
                    int f = c >> 6, lane = c & 63;
                    int ks = f / 3, nt = f % 3;
                    int k0 = ks * 32 + (lane >> 4) * 8;
                    int n  = nt * 16 + (lane & 15);
                    union { v8s v; short s[8]; } u;
#pragma unroll
                    for (int j = 0; j < 8; j++)
                        u.s[j] = (n < OUT_DIM) ? f2bf(lin2[(k0 + j) * OUT_DIM + n]) : (short)0;
                    *(v8s*)(o + (size_t)(ks * 8 + nt) * 8 * 64 + (size_t)lane * 8) = u.v;
                }
            }
        }
    } else {                                          // ---- bucket fill (runs last)
        int base = (b - 3135) * 1024;
#pragma unroll
        for (int k = 0; k < 4; k++) {
            int e = base + t + k * 256;
            if (e < N_EDGES) {
                int d = __builtin_nontemporal_load(&dst[e]);
                int s = __builtin_nontemporal_load(&src[e]);
                int p = atomicAdd(&cursor[d], 1);
                if (p < CAP) csr[d * CAP + p] = (unsigned short)s;
            }
        }
    }
}

// =============================================================== k_mlp
// fused layer: agg + mm1(relu) + mm2(relu+BN). block = 256 thr (4 waves),
// tile = 16 rows. Wave w: cols [w*32, w*32+32), rows all 16.
__global__ __launch_bounds__(256) void k_mlp(const short* __restrict__ xb,
                                             const unsigned short* __restrict__ csr,
                                             const int* __restrict__ deg,
                                             const short* __restrict__ Wp1,
                                             const short* __restrict__ Wp2,
                                             const float* __restrict__ b1,
                                             const float* __restrict__ b2,
                                             const float* __restrict__ gamma,
                                             const float* __restrict__ beta,
                                             const float* __restrict__ mean,
                                             const float* __restrict__ var,
                                             const float* __restrict__ eps_arr,
                                             int layer,
                                             short* __restrict__ out,
                                             int N) {
    __shared__ short H[TROWS * LSTRIDE];      // 4352 B
    int tid = threadIdx.x, lane = tid & 63, w = tid >> 6;
    int m16 = lane & 15, quad = lane >> 4;
    int rbase = blockIdx.x * TROWS;

    // ---- phase 0: aggregate 16 rows into H (4 rows/wave, 8 gathers in flight)
    {
        float sc = 1.0f + eps_arr[layer];
        const unsigned* X = (const unsigned*)xb;
        unsigned* Hu = (unsigned*)H;
        for (int i = w; i < TROWS; i += 4) {
            int r = rbase + i;
            unsigned pk = 0;
            if (r < N) {
                int cnt = min(deg[r], CAP);
                unsigned su = X[(size_t)r * 64 + lane];
                float a0 = sc * bflo(su), a1 = sc * bfhi(su);
                int idx = (lane < cnt) ? (int)csr[r * CAP + lane] : 0;
                int j = 0;
                for (; j + 8 <= cnt; j += 8) {
                    int s0 = __shfl(idx, j, 64),     s1 = __shfl(idx, j + 1, 64);
                    int s2 = __shfl(idx, j + 2, 64), s3 = __shfl(idx, j + 3, 64);
                    int s4 = __shfl(idx, j + 4, 64), s5 = __shfl(idx, j + 5, 64);
                    int s6 = __shfl(idx, j + 6, 64), s7 = __shfl(idx, j + 7, 64);
                    unsigned u0 = X[(size_t)s0 * 64 + lane];
                    unsigned u1 = X[(size_t)s1 * 64 + lane];
                    unsigned u2 = X[(size_t)s2 * 64 + lane];
                    unsigned u3 = X[(size_t)s3 * 64 + lane];
                    unsigned u4 = X[(size_t)s4 * 64 + lane];
                    unsigned u5 = X[(size_t)s5 * 64 + lane];
                    unsigned u6 = X[(size_t)s6 * 64 + lane];
                    unsigned u7 = X[(size_t)s7 * 64 + lane];
                    a0 += bflo(u0) + bflo(u1) + bflo(u2) + bflo(u3)
                        + bflo(u4) + bflo(u5) + bflo(u6) + bflo(u7);
                    a1 += bfhi(u0) + bfhi(u1) + bfhi(u2) + bfhi(u3)
                        + bfhi(u4) + bfhi(u5) + bfhi(u6) + bfhi(u7);
                }
                if (j + 4 <= cnt) {
                    int s0 = __shfl(idx, j, 64),     s1 = __shfl(idx, j + 1, 64);
                    int s2 = __shfl(idx, j + 2, 64), s3 = __shfl(idx, j + 3, 64);
                    unsigned u0 = X[(size_t)s0 * 64 + lane];
                    unsigned u1 = X[(size_t)s1 * 64 + lane];
                    unsigned u2 = X[(size_t)s2 * 64 + lane];
                    unsigned u3 = X[(size_t)s3 * 64 + lane];
                    a0 += bflo(u0) + bflo(u1) + bflo(u2) + bflo(u3);
                    a1 += bfhi(u0) + bfhi(u1) + bfhi(u2) + bfhi(u3);
                    j += 4;
                }
                for (; j < cnt; j++) {
                    int s = __shfl(idx, j, 64);
                    unsigned u = X[(size_t)s * 64 + lane];
                    a0 += bflo(u);
                    a1 += bfhi(u);
                }
                pk = packbf(a0, a1);
            }
            Hu[i * (LSTRIDE / 2) + lane] = pk;
        }
    }
    __syncthreads();

    // ---- per-wave epilogue params
    float pb1[2], pb2[2], ps[2], pt[2];
#pragma unroll
    for (int nt = 0; nt < 2; nt++) {
        int c = w * 32 + nt * 16 + m16;
        pb1[nt] = b1[c];
        pb2[nt] = b2[c];
        float g = gamma[c];
        float iv = rsqrtf(var[c] + BN_EPS);
        ps[nt] = g * iv;
        pt[nt] = beta[c] - g * mean[c] * iv;
    }

    // ---- phase 1: H1 = relu(agg @ W1 + b1)
    v4f acc[2];
    acc[0] = {0.f, 0.f, 0.f, 0.f};
    acc[1] = {0.f, 0.f, 0.f, 0.f};

#pragma unroll
    for (int ks = 0; ks < 4; ks++) {
        v8s bfr[2];
#pragma unroll
        for (int nt = 0; nt < 2; nt++)
            bfr[nt] = ((const v8s*)Wp1)[(ks * 8 + w * 2 + nt) * 64 + lane];
        v8s a = *(const v8s*)&H[m16 * LSTRIDE + ks * 32 + quad * 8];
#pragma unroll
        for (int nt = 0; nt < 2; nt++)
            acc[nt] = __builtin_amdgcn_mfma_f32_16x16x32_bf16(a, bfr[nt], acc[nt], 0, 0, 0);
    }
    __syncthreads();

#pragma unroll
    for (int nt = 0; nt < 2; nt++)
#pragma unroll
        for (int r4 = 0; r4 < 4; r4++) {
            float y = fmaxf(acc[nt][r4] + pb1[nt], 0.f);
            H[(quad * 4 + r4) * LSTRIDE + w * 32 + nt * 16 + m16] = f2bf(y);
        }
    __syncthreads();

    // ---- phase 2: out = BN(relu(H1 @ W2 + b2))
    v4f acc2[2];
    acc2[0] = {0.f, 0.f, 0.f, 0.f};
    acc2[1] = {0.f, 0.f, 0.f, 0.f};

#pragma unroll
    for (int ks = 0; ks < 4; ks++) {
        v8s bfr[2];
#pragma unroll
        for (int nt = 0; nt < 2; nt++)
            bfr[nt] = ((const v8s*)Wp2)[(ks * 8 + w * 2 + nt) * 64 + lane];
        v8s a = *(const v8s*)&H[m16 * LSTRIDE + ks * 32 + quad * 8];
#pragma unroll
        for (int nt = 0; nt < 2; nt++)
            acc2[nt] = __builtin_amdgcn_mfma_f32_16x16x32_bf16(a, bfr[nt], acc2[nt], 0, 0, 0);
    }

#pragma unroll
    for (int r4 = 0; r4 < 4; r4++) {
        int row = rbase + quad * 4 + r4;
        if (row < N) {
#pragma unroll
            for (int nt = 0; nt < 2; nt++) {
                float y = fmaxf(acc2[nt][r4] + pb2[nt], 0.f);
                y = ps[nt] * y + pt[nt];
                out[(size_t)row * HID + w * 32 + nt * 16 + m16] = f2bf(y);
            }
        }
    }
}

// =============================================================== k_pool
__global__ __launch_bounds__(256) void k_pool(const short* __restrict__ Xs,
                                              const int* __restrict__ batch,
                                              short* __restrict__ pooled) {
    int g = blockIdx.x;
    int tid = threadIdx.x, lane = tid & 63, w = tid >> 6;
    __shared__ int sh[2];
    __shared__ float red0[256], red1[256];
    if (tid < 2) {
        int target = g + tid;
        int lo = 0, hi = N_NODES;
        while (lo < hi) {
            int mid = (lo + hi) >> 1;
            if (batch[mid] < target) lo = mid + 1; else hi = mid;
        }
        sh[tid] = lo;
    }
    __syncthreads();
    int lo = sh[0], hi = sh[1];
    const unsigned* X = (const unsigned*)Xs;
    float a0 = 0.f, a1 = 0.f;
    for (int r = lo + w; r < hi; r += 4) {
        unsigned u = X[(size_t)r * 64 + lane];
        a0 += bflo(u);
        a1 += bfhi(u);
    }
    red0[tid] = a0;
    red1[tid] = a1;
    __syncthreads();
    if (w == 0) {
        float s0 = red0[lane] + red0[64 + lane] + red0[128 + lane] + red0[192 + lane];
        float s1 = red1[lane] + red1[64 + lane] + red1[128 + lane] + red1[192 + lane];
        float c = fmaxf((float)(hi - lo), 1.0f);
        ((unsigned*)pooled)[g * 64 + lane] = packbf(s0 / c, s1 / c);
    }
}

// =============================================================== k_head
// 1 block: relu(pooled@lin1+b) -> LDS -> @lin2+b2 -> log_softmax -> out
__global__ __launch_bounds__(256) void k_head(const short* __restrict__ pooled,
                                              const short* __restrict__ Wp8,
                                              const short* __restrict__ Wp9,
                                              const float* __restrict__ b1h,
                                              const float* __restrict__ b2h,
                                              float* __restrict__ out) {
    __shared__ short Hl[128 * LSTRIDE];       // 34816 B
    __shared__ float Ll[128 * OUT_DIM];       // 20480 B
    int tid = threadIdx.x, lane = tid & 63, w = tid >> 6;
    int m16 = lane & 15, quad = lane >> 4;

    // ---- mm1: wave w: rows (w>>1)*64, cols (w&1)*64
    {
        int nh = w & 1, mh = w >> 1, base = mh * 64;
        float pb[4];
#pragma unroll
        for (int nt = 0; nt < 4; nt++) pb[nt] = b1h[nh * 64 + nt * 16 + m16];
        v4f acc[4][4];
#pragma unroll
        for (int mt = 0; mt < 4; mt++)
#pragma unroll
            for (int nt = 0; nt < 4; nt++) acc[mt][nt] = {0.f, 0.f, 0.f, 0.f};
#pragma unroll
        for (int ks = 0; ks < 4; ks++) {
            v8s bfr[4];
#pragma unroll
            for (int nt = 0; nt < 4; nt++)
                bfr[nt] = ((const v8s*)Wp8)[(ks * 8 + nh * 4 + nt) * 64 + lane];
#pragma unroll
            for (int mt = 0; mt < 4; mt++) {
                v8s a = *(const v8s*)(pooled + (size_t)(base + mt * 16 + m16) * HID
                                      + ks * 32 + quad * 8);
#pragma unroll
                for (int nt = 0; nt < 4; nt++)
                    acc[mt][nt] = __builtin_amdgcn_mfma_f32_16x16x32_bf16(a, bfr[nt], acc[mt][nt], 0, 0, 0);
            }
        }
#pragma unroll
        for (int mt = 0; mt < 4; mt++)
#pragma unroll
            for (int r4 = 0; r4 < 4; r4++) {
                int row = base + mt * 16 + quad * 4 + r4;
#pragma unroll
                for (int nt = 0; nt < 4; nt++)
                    Hl[row * LSTRIDE + nh * 64 + nt * 16 + m16] =
                        f2bf(fmaxf(acc[mt][nt][r4] + pb[nt], 0.f));
            }
    }
    __syncthreads();

    // ---- mm2: wave w: rows w*32..+32, cols 0..47 (only <40 kept)
    {
        v4f acc[2][3];
#pragma unroll
        for (int mt = 0; mt < 2; mt++)
#pragma unroll
            for (int nt = 0; nt < 3; nt++) acc[mt][nt] = {0.f, 0.f, 0.f, 0.f};
#pragma unroll
        for (int ks = 0; ks < 4; ks++) {
            v8s bfr[3];
#pragma unroll
            for (int nt = 0; nt < 3; nt++)
                bfr[nt] = ((const v8s*)Wp9)[(ks * 8 + nt) * 64 + lane];
#pragma unroll
            for (int mt = 0; mt < 2; mt++) {
                v8s a = *(const v8s*)&Hl[(w * 32 + mt * 16 + m16) * LSTRIDE + ks * 32 + quad * 8];
#pragma unroll
                for (int nt = 0; nt < 3; nt++)
                    acc[mt][nt] = __builtin_amdgcn_mfma_f32_16x16x32_bf16(a, bfr[nt], acc[mt][nt], 0, 0, 0);
            }
        }
#pragma unroll
        for (int mt = 0; mt < 2; mt++)
#pragma unroll
            for (int r4 = 0; r4 < 4; r4++) {
                int row = w * 32 + mt * 16 + quad * 4 + r4;
#pragma unroll
                for (int nt = 0; nt < 3; nt++) {
                    int col = nt * 16 + m16;
                    if (col < OUT_DIM)
                        Ll[row * OUT_DIM + col] = acc[mt][nt][r4] + b2h[col];
                }
            }
    }
    __syncthreads();

    // ---- log_softmax per graph (32 graphs / wave)
    for (int g = w; g < N_GRAPHS; g += 4) {
        float a = (lane < OUT_DIM) ? Ll[g * OUT_DIM + lane] : -INFINITY;
        float v = a;
        for (int d = 32; d > 0; d >>= 1) v = fmaxf(v, __shfl_xor(v, d, 64));
        float ex = (lane < OUT_DIM) ? expf(a - v) : 0.0f;
        float s = ex;
        for (int d = 32; d > 0; d >>= 1) s += __shfl_xor(s, d, 64);
        if (lane < OUT_DIM) out[g * OUT_DIM + lane] = a - v - logf(s);
    }
}

// ----------------------------------------------------------------- launcher
extern "C" void kernel_launch(void* const* d_in, const int* in_sizes, int n_in,
                              void* d_out, int out_size, void* d_ws, size_t ws_size,
                              hipStream_t stream) {
    const float* x       = (const float*)d_in[0];
    const int*   edge    = (const int*)d_in[1];
    const int*   batch   = (const int*)d_in[2];
    const float* W1s     = (const float*)d_in[3];
    const float* b1s     = (const float*)d_in[4];
    const float* W2s     = (const float*)d_in[5];
    const float* b2s     = (const float*)d_in[6];
    const float* gammas  = (const float*)d_in[7];
    const float* betas   = (const float*)d_in[8];
    const float* bn_m    = (const float*)d_in[9];
    const float* bn_v    = (const float*)d_in[10];
    const float* eps_arr = (const float*)d_in[11];
    const float* lin1_W  = (const float*)d_in[12];
    const float* lin1_b  = (const float*)d_in[13];
    const float* lin2_W  = (const float*)d_in[14];
    const float* lin2_b  = (const float*)d_in[15];

    const int* src = edge;
    const int* dst = edge + N_EDGES;

    // workspace layout (≈ 32.6 MB)
    short* bufA    = (short*)d_ws;                        // 50000*128 bf16
    short* bufB    = bufA + (size_t)N_NODES * HID;
    short* Wp      = bufB + (size_t)N_NODES * HID;        // 10 slots * 16384 bf16
    short* pooled  = Wp + 10 * 16384;                     // 128*128 bf16
    int*   cursor  = (int*)(pooled + N_GRAPHS * HID);     // 50000 (degree after fill)
    unsigned short* csr = (unsigned short*)(cursor + N_NODES);   // 50000*CAP ushort

    // ---- zero cursor, then fused pre-pass (x2b NT + weight prep + fill last)
    (void)hipMemsetAsync(cursor, 0, N_NODES * sizeof(int), stream);
    k_pre<<<3917, 256, 0, stream>>>(x, (unsigned*)bufA, src, dst, cursor, csr,
                                    W1s, W2s, lin1_W, lin2_W, Wp);

    // ---- fused GIN layers
    const int mlpBlocks = (N_NODES + TROWS - 1) / TROWS;   // 3125
    short* in   = bufA;
    short* outb = bufB;
    for (int l = 0; l < N_LAYERS; l++) {
        k_mlp<<<mlpBlocks, 256, 0, stream>>>(in, csr, cursor,
                                             Wp + (size_t)l * 16384,
                                             Wp + (size_t)(4 + l) * 16384,
                                             b1s + l * HID, b2s + l * HID,
                                             gammas + l * HID, betas + l * HID,
                                             bn_m + l * HID, bn_v + l * HID,
                                             eps_arr, l, outb, N_NODES);
        short* tmp = in; in = outb; outb = tmp;
    }

    // ---- pool + head
    k_pool<<<N_GRAPHS, 256, 0, stream>>>(in, batch, pooled);
    k_head<<<1, 256, 0, stream>>>(pooled, Wp + (size_t)8 * 16384, Wp + (size_t)9 * 16384,
                                  lin1_b, lin2_b, (float*)d_out);
}

// Round 9
// 368.759 us; speedup vs baseline: 1.0182x; 1.0182x over previous
//
#include <hip/hip_runtime.h>
#include <hip/hip_bf16.h>
#include <math.h>

#define N_NODES  50000
#define N_EDGES  800000
#define HID      128
#define OUT_DIM  40
#define N_LAYERS 4
#define N_GRAPHS 128
#define BN_EPS   1e-5f
#define TROWS    32     // rows per k_mlp block
#define LSTRIDE  136    // LDS row stride in shorts (16B-aligned, 2-way bank alias only)
#define CAP      64     // csr bucket capacity (Poisson(16): P(deg>=64) ~ 2e-18)

typedef short v8s __attribute__((ext_vector_type(8)));
typedef float v4f __attribute__((ext_vector_type(4)));

static __device__ __forceinline__ short f2bf(float f) {
    __hip_bfloat16 h = __float2bfloat16(f);
    return __builtin_bit_cast(short, h);
}
static __device__ __forceinline__ float bflo(unsigned u) {
    return __builtin_bit_cast(float, u << 16);
}
static __device__ __forceinline__ float bfhi(unsigned u) {
    return __builtin_bit_cast(float, u & 0xffff0000u);
}
static __device__ __forceinline__ unsigned packbf(float a0, float a1) {
    return ((unsigned)(unsigned short)f2bf(a1) << 16) | (unsigned)(unsigned short)f2bf(a0);
}

// =============================================================== k_pre (R6 structure)
//  blocks [0, 782)      : bucket fill (runs first, overlaps x2b; cursor -> degree)
//  blocks [782, 3907)   : x fp32 -> packed bf16, uint4 stores
//  blocks [3907, 3917)  : weight frag-pack (9 full mats + head W2 zero-padded)
__global__ __launch_bounds__(256) void k_pre(const float* __restrict__ x,
                                             unsigned* __restrict__ xb,
                                             const int* __restrict__ src,
                                             const int* __restrict__ dst,
                                             int* __restrict__ cursor,
                                             unsigned short* __restrict__ csr,
                                             const float* __restrict__ W1s,
                                             const float* __restrict__ W2s,
                                             const float* __restrict__ lin1,
                                             const float* __restrict__ lin2,
                                             short* __restrict__ Wp) {
    int b = blockIdx.x, t = threadIdx.x;
    if (b < 782) {                                    // ---- bucket fill
        int base = b * 1024;
#pragma unroll
        for (int k = 0; k < 4; k++) {
            int e = base + t + k * 256;
            if (e < N_EDGES) {
                int d = dst[e];
                int p = atomicAdd(&cursor[d], 1);
                if (p < CAP) csr[d * CAP + p] = (unsigned short)src[e];
            }
        }
    } else if (b < 3907) {                            // ---- x2b (16B stores)
        int j = (b - 782) * 256 + t;                  // 0 .. 799999
        const float4* x4 = (const float4*)x;
        float4 f0 = x4[2 * j];
        float4 f1 = x4[2 * j + 1];
        uint4 o;
        o.x = packbf(f0.x, f0.y);
        o.y = packbf(f0.z, f0.w);
        o.z = packbf(f1.x, f1.y);
        o.w = packbf(f1.z, f1.w);
        ((uint4*)xb)[j] = o;
    } else {                                          // ---- weight prep
        int bp = b - 3907;
        if (bp < 9) {
            const float* W = (bp < 4) ? (W1s + bp * 16384)
                           : (bp < 8) ? (W2s + (bp - 4) * 16384)
                                      : lin1;
            short* o = Wp + (size_t)bp * 16384;
#pragma unroll
            for (int i = 0; i < 8; i++) {
                int c = i * 256 + t;                  // chunk 0..2047
                int f = c >> 6, lane = c & 63;
                int ks = f >> 3, nt = f & 7;
                int k0 = ks * 32 + (lane >> 4) * 8;
                int n  = nt * 16 + (lane & 15);
                union { v8s v; short s[8]; } u;
#pragma unroll
                for (int j = 0; j < 8; j++) u.s[j] = f2bf(W[(k0 + j) * 128 + n]);
                *(v8s*)(o + (size_t)c * 8) = u.v;
            }
        } else {                                      // head W2 [128][40] -> frags, pad->0
            short* o = Wp + (size_t)9 * 16384;
#pragma unroll
            for (int i = 0; i < 3; i++) {
                int c = i * 256 + t;
                if (c < 768) {
                    int f = c >> 6, lane = c & 63;
                    int ks = f / 3, nt = f % 3;
                    int k0 = ks * 32 + (lane >> 4) * 8;
                    int n  = nt * 16 + (lane & 15);
                    union { v8s v; short s[8]; } u;
#pragma unroll
                    for (int j = 0; j < 8; j++)
                        u.s[j] = (n < OUT_DIM) ? f2bf(lin2[(k0 + j) * OUT_DIM + n]) : (short)0;
                    *(v8s*)(o + (size_t)(ks * 8 + nt) * 8 * 64 + (size_t)lane * 8) = u.v;
                }
            }
        }
    }
}

// =============================================================== k_mlp
// fused layer: agg + mm1(relu) + mm2(relu+BN [+pool]). block = 256 thr (4 waves),
// tile = 32 rows. Wave w: cols [w*32, w*32+32), rows all 32.
// lastL=0: store features. lastL=1: skip store, atomically accumulate per-graph
// column sums into pooledF (mean-pool fused; counts handled in k_head).
__global__ __launch_bounds__(256) void k_mlp(const short* __restrict__ xb,
                                             const unsigned short* __restrict__ csr,
                                             const int* __restrict__ deg,
                                             const short* __restrict__ Wp1,
                                             const short* __restrict__ Wp2,
                                             const float* __restrict__ b1,
                                             const float* __restrict__ b2,
                                             const float* __restrict__ gamma,
                                             const float* __restrict__ beta,
                                             const float* __restrict__ mean,
                                             const float* __restrict__ var,
                                             const float* __restrict__ eps_arr,
                                             int layer,
                                             short* __restrict__ out,
                                             const int* __restrict__ batch,
                                             float* __restrict__ pooledF,
                                             int lastL,
                                             int N) {
    __shared__ short H[TROWS * LSTRIDE];      // 8704 B
    int tid = threadIdx.x, lane = tid & 63, w = tid >> 6;
    int m16 = lane & 15, quad = lane >> 4;
    int rbase = blockIdx.x * TROWS;

    // ---- phase 0: aggregate 32 rows into H (8 rows/wave, 8 gathers in flight)
    {
        float sc = 1.0f + eps_arr[layer];
        const unsigned* X = (const unsigned*)xb;
        unsigned* Hu = (unsigned*)H;
        for (int i = w; i < TROWS; i += 4) {
            int r = rbase + i;
            unsigned pk = 0;
            if (r < N) {
                int cnt = min(deg[r], CAP);
                unsigned su = X[(size_t)r * 64 + lane];
                float a0 = sc * bflo(su), a1 = sc * bfhi(su);
                int idx = (lane < cnt) ? (int)csr[r * CAP + lane] : 0;
                int j = 0;
                for (; j + 8 <= cnt; j += 8) {
                    int s0 = __shfl(idx, j, 64),     s1 = __shfl(idx, j + 1, 64);
                    int s2 = __shfl(idx, j + 2, 64), s3 = __shfl(idx, j + 3, 64);
                    int s4 = __shfl(idx, j + 4, 64), s5 = __shfl(idx, j + 5, 64);
                    int s6 = __shfl(idx, j + 6, 64), s7 = __shfl(idx, j + 7, 64);
                    unsigned u0 = X[(size_t)s0 * 64 + lane];
                    unsigned u1 = X[(size_t)s1 * 64 + lane];
                    unsigned u2 = X[(size_t)s2 * 64 + lane];
                    unsigned u3 = X[(size_t)s3 * 64 + lane];
                    unsigned u4 = X[(size_t)s4 * 64 + lane];
                    unsigned u5 = X[(size_t)s5 * 64 + lane];
                    unsigned u6 = X[(size_t)s6 * 64 + lane];
                    unsigned u7 = X[(size_t)s7 * 64 + lane];
                    a0 += bflo(u0) + bflo(u1) + bflo(u2) + bflo(u3)
                        + bflo(u4) + bflo(u5) + bflo(u6) + bflo(u7);
                    a1 += bfhi(u0) + bfhi(u1) + bfhi(u2) + bfhi(u3)
                        + bfhi(u4) + bfhi(u5) + bfhi(u6) + bfhi(u7);
                }
                if (j + 4 <= cnt) {
                    int s0 = __shfl(idx, j, 64),     s1 = __shfl(idx, j + 1, 64);
                    int s2 = __shfl(idx, j + 2, 64), s3 = __shfl(idx, j + 3, 64);
                    unsigned u0 = X[(size_t)s0 * 64 + lane];
                    unsigned u1 = X[(size_t)s1 * 64 + lane];
                    unsigned u2 = X[(size_t)s2 * 64 + lane];
                    unsigned u3 = X[(size_t)s3 * 64 + lane];
                    a0 += bflo(u0) + bflo(u1) + bflo(u2) + bflo(u3);
                    a1 += bfhi(u0) + bfhi(u1) + bfhi(u2) + bfhi(u3);
                    j += 4;
                }
                for (; j < cnt; j++) {
                    int s = __shfl(idx, j, 64);
                    unsigned u = X[(size_t)s * 64 + lane];
                    a0 += bflo(u);
                    a1 += bfhi(u);
                }
                pk = packbf(a0, a1);
            }
            Hu[i * (LSTRIDE / 2) + lane] = pk;
        }
    }
    __syncthreads();

    // ---- per-wave epilogue params
    float pb1[2], pb2[2], ps[2], pt[2];
#pragma unroll
    for (int nt = 0; nt < 2; nt++) {
        int c = w * 32 + nt * 16 + m16;
        pb1[nt] = b1[c];
        pb2[nt] = b2[c];
        float g = gamma[c];
        float iv = rsqrtf(var[c] + BN_EPS);
        ps[nt] = g * iv;
        pt[nt] = beta[c] - g * mean[c] * iv;
    }

    // ---- phase 1: H1 = relu(agg @ W1 + b1)
    v4f acc[2][2];
#pragma unroll
    for (int mt = 0; mt < 2; mt++)
#pragma unroll
        for (int nt = 0; nt < 2; nt++) acc[mt][nt] = {0.f, 0.f, 0.f, 0.f};

#pragma unroll
    for (int ks = 0; ks < 4; ks++) {
        v8s bfr[2];
#pragma unroll
        for (int nt = 0; nt < 2; nt++)
            bfr[nt] = ((const v8s*)Wp1)[(ks * 8 + w * 2 + nt) * 64 + lane];
#pragma unroll
        for (int mt = 0; mt < 2; mt++) {
            v8s a = *(const v8s*)&H[(mt * 16 + m16) * LSTRIDE + ks * 32 + quad * 8];
#pragma unroll
            for (int nt = 0; nt < 2; nt++)
                acc[mt][nt] = __builtin_amdgcn_mfma_f32_16x16x32_bf16(a, bfr[nt], acc[mt][nt], 0, 0, 0);
        }
    }
    __syncthreads();

#pragma unroll
    for (int mt = 0; mt < 2; mt++)
#pragma unroll
        for (int nt = 0; nt < 2; nt++)
#pragma unroll
            for (int r4 = 0; r4 < 4; r4++) {
                float y = fmaxf(acc[mt][nt][r4] + pb1[nt], 0.f);
                H[(mt * 16 + quad * 4 + r4) * LSTRIDE + w * 32 + nt * 16 + m16] = f2bf(y);
            }
    __syncthreads();

    // ---- phase 2: y = BN(relu(H1 @ W2 + b2))
    v4f acc2[2][2];
#pragma unroll
    for (int mt = 0; mt < 2; mt++)
#pragma unroll
        for (int nt = 0; nt < 2; nt++) acc2[mt][nt] = {0.f, 0.f, 0.f, 0.f};

#pragma unroll
    for (int ks = 0; ks < 4; ks++) {
        v8s bfr[2];
#pragma unroll
        for (int nt = 0; nt < 2; nt++)
            bfr[nt] = ((const v8s*)Wp2)[(ks * 8 + w * 2 + nt) * 64 + lane];
#pragma unroll
        for (int mt = 0; mt < 2; mt++) {
            v8s a = *(const v8s*)&H[(mt * 16 + m16) * LSTRIDE + ks * 32 + quad * 8];
#pragma unroll
            for (int nt = 0; nt < 2; nt++)
                acc2[mt][nt] = __builtin_amdgcn_mfma_f32_16x16x32_bf16(a, bfr[nt], acc2[mt][nt], 0, 0, 0);
        }
    }

    if (!lastL) {
#pragma unroll
        for (int mt = 0; mt < 2; mt++)
#pragma unroll
            for (int r4 = 0; r4 < 4; r4++) {
                int row = rbase + mt * 16 + quad * 4 + r4;
                if (row < N) {
#pragma unroll
                    for (int nt = 0; nt < 2; nt++) {
                        float y = fmaxf(acc2[mt][nt][r4] + pb2[nt], 0.f);
                        y = ps[nt] * y + pt[nt];
                        out[(size_t)row * HID + w * 32 + nt * 16 + m16] = f2bf(y);
                    }
                }
            }
    } else {
        // ---- fused mean-pool (sums; divide in k_head)
        bool fast = (rbase + TROWS <= N) && (batch[rbase] == batch[rbase + TROWS - 1]);
        if (fast) {
            int g = batch[rbase];
#pragma unroll
            for (int nt = 0; nt < 2; nt++) {
                float v = 0.f;
#pragma unroll
                for (int mt = 0; mt < 2; mt++)
#pragma unroll
                    for (int r4 = 0; r4 < 4; r4++) {
                        float y = fmaxf(acc2[mt][nt][r4] + pb2[nt], 0.f);
                        v += ps[nt] * y + pt[nt];
                    }
                v += __shfl_xor(v, 16, 64);
                v += __shfl_xor(v, 32, 64);
                if (quad == 0)
                    atomicAdd(&pooledF[g * HID + w * 32 + nt * 16 + m16], v);
            }
        } else {
#pragma unroll
            for (int mt = 0; mt < 2; mt++)
#pragma unroll
                for (int r4 = 0; r4 < 4; r4++) {
                    int row = rbase + mt * 16 + quad * 4 + r4;
                    if (row < N) {
                        int g = batch[row];
#pragma unroll
                        for (int nt = 0; nt < 2; nt++) {
                            float y = fmaxf(acc2[mt][nt][r4] + pb2[nt], 0.f);
                            y = ps[nt] * y + pt[nt];
                            atomicAdd(&pooledF[g * HID + w * 32 + nt * 16 + m16], y);
                        }
                    }
                }
        }
    }
}

// =============================================================== k_head
// 1 block: mean = pooledF/count -> LDS(bf16 A) -> relu(@lin1+b) -> LDS ->
// @lin2+b2 -> log_softmax -> out
__global__ __launch_bounds__(256) void k_head(const float* __restrict__ pooledF,
                                              const int* __restrict__ batch,
                                              const short* __restrict__ Wp8,
                                              const short* __restrict__ Wp9,
                                              const float* __restrict__ b1h,
                                              const float* __restrict__ b2h,
                                              float* __restrict__ out) {
    __shared__ short Al[128 * LSTRIDE];       // 34816 B  (pooled means, bf16)
    __shared__ short Hl[128 * LSTRIDE];       // 34816 B  (hidden)
    __shared__ float Ll[128 * OUT_DIM];       // 20480 B  (logits)
    __shared__ float invc[N_GRAPHS];
    int tid = threadIdx.x, lane = tid & 63, w = tid >> 6;
    int m16 = lane & 15, quad = lane >> 4;

    // ---- per-graph counts (sorted batch, two binary searches per graph)
    if (tid < N_GRAPHS) {
        int g = tid, lo = 0, hi = N_NODES;
        while (lo < hi) { int m = (lo + hi) >> 1; if (batch[m] < g) lo = m + 1; else hi = m; }
        int s = lo; lo = 0; hi = N_NODES;
        while (lo < hi) { int m = (lo + hi) >> 1; if (batch[m] < g + 1) lo = m + 1; else hi = m; }
        invc[g] = 1.0f / fmaxf((float)(lo - s), 1.0f);
    }
    __syncthreads();

    // ---- means -> Al (bf16)
    for (int i = tid; i < N_GRAPHS * HID; i += 256) {
        int row = i >> 7, col = i & 127;
        Al[row * LSTRIDE + col] = f2bf(pooledF[i] * invc[row]);
    }
    __syncthreads();

    // ---- mm1: wave w: rows (w>>1)*64, cols (w&1)*64
    {
        int nh = w & 1, mh = w >> 1, base = mh * 64;
        float pb[4];
#pragma unroll
        for (int nt = 0; nt < 4; nt++) pb[nt] = b1h[nh * 64 + nt * 16 + m16];
        v4f acc[4][4];
#pragma unroll
        for (int mt = 0; mt < 4; mt++)
#pragma unroll
            for (int nt = 0; nt < 4; nt++) acc[mt][nt] = {0.f, 0.f, 0.f, 0.f};
#pragma unroll
        for (int ks = 0; ks < 4; ks++) {
            v8s bfr[4];
#pragma unroll
            for (int nt = 0; nt < 4; nt++)
                bfr[nt] = ((const v8s*)Wp8)[(ks * 8 + nh * 4 + nt) * 64 + lane];
#pragma unroll
            for (int mt = 0; mt < 4; mt++) {
                v8s a = *(const v8s*)&Al[(base + mt * 16 + m16) * LSTRIDE + ks * 32 + quad * 8];
#pragma unroll
                for (int nt = 0; nt < 4; nt++)
                    acc[mt][nt] = __builtin_amdgcn_mfma_f32_16x16x32_bf16(a, bfr[nt], acc[mt][nt], 0, 0, 0);
            }
        }
#pragma unroll
        for (int mt = 0; mt < 4; mt++)
#pragma unroll
            for (int r4 = 0; r4 < 4; r4++) {
                int row = base + mt * 16 + quad * 4 + r4;
#pragma unroll
                for (int nt = 0; nt < 4; nt++)
                    Hl[row * LSTRIDE + nh * 64 + nt * 16 + m16] =
                        f2bf(fmaxf(acc[mt][nt][r4] + pb[nt], 0.f));
            }
    }
    __syncthreads();

    // ---- mm2: wave w: rows w*32..+32, cols 0..47 (only <40 kept)
    {
        v4f acc[2][3];
#pragma unroll
        for (int mt = 0; mt < 2; mt++)
#pragma unroll
            for (int nt = 0; nt < 3; nt++) acc[mt][nt] = {0.f, 0.f, 0.f, 0.f};
#pragma unroll
        for (int ks = 0; ks < 4; ks++) {
            v8s bfr[3];
#pragma unroll
            for (int nt = 0; nt < 3; nt++)
                bfr[nt] = ((const v8s*)Wp9)[(ks * 8 + nt) * 64 + lane];
#pragma unroll
            for (int mt = 0; mt < 2; mt++) {
                v8s a = *(const v8s*)&Hl[(w * 32 + mt * 16 + m16) * LSTRIDE + ks * 32 + quad * 8];
#pragma unroll
                for (int nt = 0; nt < 3; nt++)
                    acc[mt][nt] = __builtin_amdgcn_mfma_f32_16x16x32_bf16(a, bfr[nt], acc[mt][nt], 0, 0, 0);
            }
        }
#pragma unroll
        for (int mt = 0; mt < 2; mt++)
#pragma unroll
            for (int r4 = 0; r4 < 4; r4++) {
                int row = w * 32 + mt * 16 + quad * 4 + r4;
#pragma unroll
                for (int nt = 0; nt < 3; nt++) {
                    int col = nt * 16 + m16;
                    if (col < OUT_DIM)
                        Ll[row * OUT_DIM + col] = acc[mt][nt][r4] + b2h[col];
                }
            }
    }
    __syncthreads();

    // ---- log_softmax per graph (32 graphs / wave)
    for (int g = w; g < N_GRAPHS; g += 4) {
        float a = (lane < OUT_DIM) ? Ll[g * OUT_DIM + lane] : -INFINITY;
        float v = a;
        for (int d = 32; d > 0; d >>= 1) v = fmaxf(v, __shfl_xor(v, d, 64));
        float ex = (lane < OUT_DIM) ? expf(a - v) : 0.0f;
        float s = ex;
        for (int d = 32; d > 0; d >>= 1) s += __shfl_xor(s, d, 64);
        if (lane < OUT_DIM) out[g * OUT_DIM + lane] = a - v - logf(s);
    }
}

// ----------------------------------------------------------------- launcher
extern "C" void kernel_launch(void* const* d_in, const int* in_sizes, int n_in,
                              void* d_out, int out_size, void* d_ws, size_t ws_size,
                              hipStream_t stream) {
    const float* x       = (const float*)d_in[0];
    const int*   edge    = (const int*)d_in[1];
    const int*   batch   = (const int*)d_in[2];
    const float* W1s     = (const float*)d_in[3];
    const float* b1s     = (const float*)d_in[4];
    const float* W2s     = (const float*)d_in[5];
    const float* b2s     = (const float*)d_in[6];
    const float* gammas  = (const float*)d_in[7];
    const float* betas   = (const float*)d_in[8];
    const float* bn_m    = (const float*)d_in[9];
    const float* bn_v    = (const float*)d_in[10];
    const float* eps_arr = (const float*)d_in[11];
    const float* lin1_W  = (const float*)d_in[12];
    const float* lin1_b  = (const float*)d_in[13];
    const float* lin2_W  = (const float*)d_in[14];
    const float* lin2_b  = (const float*)d_in[15];

    const int* src = edge;
    const int* dst = edge + N_EDGES;

    // workspace layout (≈ 32.7 MB); cursor+pooledF adjacent for one memset
    short* bufA    = (short*)d_ws;                        // 50000*128 bf16
    short* bufB    = bufA + (size_t)N_NODES * HID;
    short* Wp      = bufB + (size_t)N_NODES * HID;        // 10 slots * 16384 bf16
    int*   cursor  = (int*)(Wp + 10 * 16384);             // 50000 (degree after fill)
    float* pooledF = (float*)(cursor + N_NODES);          // 128*128 fp32 (pool sums)
    unsigned short* csr = (unsigned short*)(pooledF + N_GRAPHS * HID);  // 50000*CAP

    // ---- zero cursor + pooledF in one shot, then fused pre-pass
    (void)hipMemsetAsync(cursor, 0, (N_NODES + N_GRAPHS * HID) * sizeof(int), stream);
    k_pre<<<3917, 256, 0, stream>>>(x, (unsigned*)bufA, src, dst, cursor, csr,
                                    W1s, W2s, lin1_W, lin2_W, Wp);

    // ---- fused GIN layers (layer 3 pools instead of storing)
    const int mlpBlocks = (N_NODES + TROWS - 1) / TROWS;   // 1563
    short* in   = bufA;
    short* outb = bufB;
    for (int l = 0; l < N_LAYERS; l++) {
        int lastL = (l == N_LAYERS - 1) ? 1 : 0;
        k_mlp<<<mlpBlocks, 256, 0, stream>>>(in, csr, cursor,
                                             Wp + (size_t)l * 16384,
                                             Wp + (size_t)(4 + l) * 16384,
                                             b1s + l * HID, b2s + l * HID,
                                             gammas + l * HID, betas + l * HID,
                                             bn_m + l * HID, bn_v + l * HID,
                                             eps_arr, l, outb, batch, pooledF,
                                             lastL, N_NODES);
        short* tmp = in; in = outb; outb = tmp;
    }

    // ---- head (counts + mean + lin1 + lin2 + log_softmax)
    k_head<<<1, 256, 0, stream>>>(pooledF, batch, Wp + (size_t)8 * 16384,
                                  Wp + (size_t)9 * 16384, lin1_b, lin2_b,
                                  (float*)d_out);
}

// Round 10
// 334.141 us; speedup vs baseline: 1.1237x; 1.1036x over previous
//
#include <hip/hip_runtime.h>
#include <hip/hip_bf16.h>
#include <math.h>

#define N_NODES  50000
#define N_EDGES  800000
#define HID      128
#define OUT_DIM  40
#define N_LAYERS 4
#define N_GRAPHS 128
#define BN_EPS   1e-5f
#define TROWS    32     // rows per k_mlp block
#define LSTRIDE  136    // LDS row stride in shorts (16B-aligned, 2-way bank alias only)
#define CAP      64     // csr bucket capacity (Poisson(16): P(deg>=64) ~ 2e-18)

typedef short v8s __attribute__((ext_vector_type(8)));
typedef float v4f __attribute__((ext_vector_type(4)));
typedef unsigned v4u __attribute__((ext_vector_type(4)));

static __device__ __forceinline__ short f2bf(float f) {
    __hip_bfloat16 h = __float2bfloat16(f);
    return __builtin_bit_cast(short, h);
}
static __device__ __forceinline__ float bflo(unsigned u) {
    return __builtin_bit_cast(float, u << 16);
}
static __device__ __forceinline__ float bfhi(unsigned u) {
    return __builtin_bit_cast(float, u & 0xffff0000u);
}
static __device__ __forceinline__ unsigned packbf(float a0, float a1) {
    return ((unsigned)(unsigned short)f2bf(a1) << 16) | (unsigned)(unsigned short)f2bf(a0);
}

// =============================================================== k_pre (R6 structure)
//  blocks [0, 782)      : bucket fill (runs first, overlaps x2b; cursor -> degree)
//  blocks [782, 3907)   : x fp32 -> packed bf16, uint4 stores
//  blocks [3907, 3917)  : weight frag-pack (9 full mats + head W2 zero-padded)
__global__ __launch_bounds__(256) void k_pre(const float* __restrict__ x,
                                             unsigned* __restrict__ xb,
                                             const int* __restrict__ src,
                                             const int* __restrict__ dst,
                                             int* __restrict__ cursor,
                                             unsigned short* __restrict__ csr,
                                             const float* __restrict__ W1s,
                                             const float* __restrict__ W2s,
                                             const float* __restrict__ lin1,
                                             const float* __restrict__ lin2,
                                             short* __restrict__ Wp) {
    int b = blockIdx.x, t = threadIdx.x;
    if (b < 782) {                                    // ---- bucket fill
        int base = b * 1024;
#pragma unroll
        for (int k = 0; k < 4; k++) {
            int e = base + t + k * 256;
            if (e < N_EDGES) {
                int d = dst[e];
                int p = atomicAdd(&cursor[d], 1);
                if (p < CAP) csr[d * CAP + p] = (unsigned short)src[e];
            }
        }
    } else if (b < 3907) {                            // ---- x2b (16B stores)
        int j = (b - 782) * 256 + t;                  // 0 .. 799999
        const float4* x4 = (const float4*)x;
        float4 f0 = x4[2 * j];
        float4 f1 = x4[2 * j + 1];
        uint4 o;
        o.x = packbf(f0.x, f0.y);
        o.y = packbf(f0.z, f0.w);
        o.z = packbf(f1.x, f1.y);
        o.w = packbf(f1.z, f1.w);
        ((uint4*)xb)[j] = o;
    } else {                                          // ---- weight prep
        int bp = b - 3907;
        if (bp < 9) {
            const float* W = (bp < 4) ? (W1s + bp * 16384)
                           : (bp < 8) ? (W2s + (bp - 4) * 16384)
                                      : lin1;
            short* o = Wp + (size_t)bp * 16384;
#pragma unroll
            for (int i = 0; i < 8; i++) {
                int c = i * 256 + t;                  // chunk 0..2047
                int f = c >> 6, lane = c & 63;
                int ks = f >> 3, nt = f & 7;
                int k0 = ks * 32 + (lane >> 4) * 8;
                int n  = nt * 16 + (lane & 15);
                union { v8s v; short s[8]; } u;
#pragma unroll
                for (int j = 0; j < 8; j++) u.s[j] = f2bf(W[(k0 + j) * 128 + n]);
                *(v8s*)(o + (size_t)c * 8) = u.v;
            }
        } else {                                      // head W2 [128][40] -> frags, pad->0
            short* o = Wp + (size_t)9 * 16384;
#pragma unroll
            for (int i = 0; i < 3; i++) {
                int c = i * 256 + t;
                if (c < 768) {
                    int f = c >> 6, lane = c & 63;
                    int ks = f / 3, nt = f % 3;
                    int k0 = ks * 32 + (lane >> 4) * 8;
                    int n  = nt * 16 + (lane & 15);
                    union { v8s v; short s[8]; } u;
#pragma unroll
                    for (int j = 0; j < 8; j++)
                        u.s[j] = (n < OUT_DIM) ? f2bf(lin2[(k0 + j) * OUT_DIM + n]) : (short)0;
                    *(v8s*)(o + (size_t)(ks * 8 + nt) * 8 * 64 + (size_t)lane * 8) = u.v;
                }
            }
        }
    }
}

// =============================================================== k_mlp
// fused layer: agg + mm1(relu) + mm2(relu+BN). block = 256 thr (4 waves),
// tile = 32 rows. Gather: 16 lanes per edge-row (dwordx4), 4 edges in
// parallel per wave iteration, 2 independent loads in flight, masked-fma tail.
__global__ __launch_bounds__(256) void k_mlp(const short* __restrict__ xb,
                                             const unsigned short* __restrict__ csr,
                                             const int* __restrict__ deg,
                                             const short* __restrict__ Wp1,
                                             const short* __restrict__ Wp2,
                                             const float* __restrict__ b1,
                                             const float* __restrict__ b2,
                                             const float* __restrict__ gamma,
                                             const float* __restrict__ beta,
                                             const float* __restrict__ mean,
                                             const float* __restrict__ var,
                                             const float* __restrict__ eps_arr,
                                             int layer,
                                             short* __restrict__ out,
                                             int N) {
    __shared__ __align__(16) short H[TROWS * LSTRIDE];   // 8704 B
    int tid = threadIdx.x, lane = tid & 63, w = tid >> 6;
    int m16 = lane & 15, quad = lane >> 4;
    int rbase = blockIdx.x * TROWS;

    // ---- phase 0: aggregate 32 rows into H
    {
        float sc = 1.0f + eps_arr[layer];
        const v4u* X4 = (const v4u*)xb;       // one row = 16 v4u (256 B)
        int g = lane >> 4, sub = lane & 15;
        for (int i = w; i < TROWS; i += 4) {
            int r = rbase + i;
            if (r >= N) {
                if (g == 0) {
                    v4u z = {0u, 0u, 0u, 0u};
                    *(v4u*)&H[i * LSTRIDE + sub * 8] = z;
                }
                continue;
            }
            int cnt = min(deg[r], CAP);
            int idx = (lane < cnt) ? (int)csr[r * CAP + lane] : 0;
            float a0 = 0.f, a1 = 0.f, a2 = 0.f, a3 = 0.f;
            float a4 = 0.f, a5 = 0.f, a6 = 0.f, a7 = 0.f;
            for (int j = 0; j < cnt; j += 8) {
                int e0 = j + g, e1 = j + 4 + g;
                float m0 = (e0 < cnt) ? 1.0f : 0.0f;
                float m1 = (e1 < cnt) ? 1.0f : 0.0f;
                int s0 = __shfl(idx, e0, 64);
                int s1 = __shfl(idx, e1, 64);
                v4u u0 = X4[(size_t)s0 * 16 + sub];
                v4u u1 = X4[(size_t)s1 * 16 + sub];
                a0 += m0 * bflo(u0.x); a1 += m0 * bfhi(u0.x);
                a2 += m0 * bflo(u0.y); a3 += m0 * bfhi(u0.y);
                a4 += m0 * bflo(u0.z); a5 += m0 * bfhi(u0.z);
                a6 += m0 * bflo(u0.w); a7 += m0 * bfhi(u0.w);
                a0 += m1 * bflo(u1.x); a1 += m1 * bfhi(u1.x);
                a2 += m1 * bflo(u1.y); a3 += m1 * bfhi(u1.y);
                a4 += m1 * bflo(u1.z); a5 += m1 * bfhi(u1.z);
                a6 += m1 * bflo(u1.w); a7 += m1 * bfhi(u1.w);
            }
            // combine the 4 edge-groups (lanes l, l^16, l^32, l^48)
            a0 += __shfl_xor(a0, 16, 64); a0 += __shfl_xor(a0, 32, 64);
            a1 += __shfl_xor(a1, 16, 64); a1 += __shfl_xor(a1, 32, 64);
            a2 += __shfl_xor(a2, 16, 64); a2 += __shfl_xor(a2, 32, 64);
            a3 += __shfl_xor(a3, 16, 64); a3 += __shfl_xor(a3, 32, 64);
            a4 += __shfl_xor(a4, 16, 64); a4 += __shfl_xor(a4, 32, 64);
            a5 += __shfl_xor(a5, 16, 64); a5 += __shfl_xor(a5, 32, 64);
            a6 += __shfl_xor(a6, 16, 64); a6 += __shfl_xor(a6, 32, 64);
            a7 += __shfl_xor(a7, 16, 64); a7 += __shfl_xor(a7, 32, 64);
            if (g == 0) {
                v4u us = X4[(size_t)r * 16 + sub];   // self term
                a0 += sc * bflo(us.x); a1 += sc * bfhi(us.x);
                a2 += sc * bflo(us.y); a3 += sc * bfhi(us.y);
                a4 += sc * bflo(us.z); a5 += sc * bfhi(us.z);
                a6 += sc * bflo(us.w); a7 += sc * bfhi(us.w);
                v4u o;
                o.x = packbf(a0, a1); o.y = packbf(a2, a3);
                o.z = packbf(a4, a5); o.w = packbf(a6, a7);
                *(v4u*)&H[i * LSTRIDE + sub * 8] = o;
            }
        }
    }
    __syncthreads();

    // ---- per-wave epilogue params
    float pb1[2], pb2[2], ps[2], pt[2];
#pragma unroll
    for (int nt = 0; nt < 2; nt++) {
        int c = w * 32 + nt * 16 + m16;
        pb1[nt] = b1[c];
        pb2[nt] = b2[c];
        float g = gamma[c];
        float iv = rsqrtf(var[c] + BN_EPS);
        ps[nt] = g * iv;
        pt[nt] = beta[c] - g * mean[c] * iv;
    }

    // ---- phase 1: H1 = relu(agg @ W1 + b1)
    v4f acc[2][2];
#pragma unroll
    for (int mt = 0; mt < 2; mt++)
#pragma unroll
        for (int nt = 0; nt < 2; nt++) acc[mt][nt] = {0.f, 0.f, 0.f, 0.f};

#pragma unroll
    for (int ks = 0; ks < 4; ks++) {
        v8s bfr[2];
#pragma unroll
        for (int nt = 0; nt < 2; nt++)
            bfr[nt] = ((const v8s*)Wp1)[(ks * 8 + w * 2 + nt) * 64 + lane];
#pragma unroll
        for (int mt = 0; mt < 2; mt++) {
            v8s a = *(const v8s*)&H[(mt * 16 + m16) * LSTRIDE + ks * 32 + quad * 8];
#pragma unroll
            for (int nt = 0; nt < 2; nt++)
                acc[mt][nt] = __builtin_amdgcn_mfma_f32_16x16x32_bf16(a, bfr[nt], acc[mt][nt], 0, 0, 0);
        }
    }
    __syncthreads();

#pragma unroll
    for (int mt = 0; mt < 2; mt++)
#pragma unroll
        for (int nt = 0; nt < 2; nt++)
#pragma unroll
            for (int r4 = 0; r4 < 4; r4++) {
                float y = fmaxf(acc[mt][nt][r4] + pb1[nt], 0.f);
                H[(mt * 16 + quad * 4 + r4) * LSTRIDE + w * 32 + nt * 16 + m16] = f2bf(y);
            }
    __syncthreads();

    // ---- phase 2: out = BN(relu(H1 @ W2 + b2))
    v4f acc2[2][2];
#pragma unroll
    for (int mt = 0; mt < 2; mt++)
#pragma unroll
        for (int nt = 0; nt < 2; nt++) acc2[mt][nt] = {0.f, 0.f, 0.f, 0.f};

#pragma unroll
    for (int ks = 0; ks < 4; ks++) {
        v8s bfr[2];
#pragma unroll
        for (int nt = 0; nt < 2; nt++)
            bfr[nt] = ((const v8s*)Wp2)[(ks * 8 + w * 2 + nt) * 64 + lane];
#pragma unroll
        for (int mt = 0; mt < 2; mt++) {
            v8s a = *(const v8s*)&H[(mt * 16 + m16) * LSTRIDE + ks * 32 + quad * 8];
#pragma unroll
            for (int nt = 0; nt < 2; nt++)
                acc2[mt][nt] = __builtin_amdgcn_mfma_f32_16x16x32_bf16(a, bfr[nt], acc2[mt][nt], 0, 0, 0);
        }
    }

#pragma unroll
    for (int mt = 0; mt < 2; mt++)
#pragma unroll
        for (int r4 = 0; r4 < 4; r4++) {
            int row = rbase + mt * 16 + quad * 4 + r4;
            if (row < N) {
#pragma unroll
                for (int nt = 0; nt < 2; nt++) {
                    float y = fmaxf(acc2[mt][nt][r4] + pb2[nt], 0.f);
                    y = ps[nt] * y + pt[nt];
                    out[(size_t)row * HID + w * 32 + nt * 16 + m16] = f2bf(y);
                }
            }
        }
}

// =============================================================== k_pool
__global__ __launch_bounds__(256) void k_pool(const short* __restrict__ Xs,
                                              const int* __restrict__ batch,
                                              short* __restrict__ pooled) {
    int g = blockIdx.x;
    int tid = threadIdx.x, lane = tid & 63, w = tid >> 6;
    __shared__ int sh[2];
    __shared__ float red0[256], red1[256];
    if (tid < 2) {
        int target = g + tid;
        int lo = 0, hi = N_NODES;
        while (lo < hi) {
            int mid = (lo + hi) >> 1;
            if (batch[mid] < target) lo = mid + 1; else hi = mid;
        }
        sh[tid] = lo;
    }
    __syncthreads();
    int lo = sh[0], hi = sh[1];
    const unsigned* X = (const unsigned*)Xs;
    float a0 = 0.f, a1 = 0.f;
    for (int r = lo + w; r < hi; r += 4) {
        unsigned u = X[(size_t)r * 64 + lane];
        a0 += bflo(u);
        a1 += bfhi(u);
    }
    red0[tid] = a0;
    red1[tid] = a1;
    __syncthreads();
    if (w == 0) {
        float s0 = red0[lane] + red0[64 + lane] + red0[128 + lane] + red0[192 + lane];
        float s1 = red1[lane] + red1[64 + lane] + red1[128 + lane] + red1[192 + lane];
        float c = fmaxf((float)(hi - lo), 1.0f);
        ((unsigned*)pooled)[g * 64 + lane] = packbf(s0 / c, s1 / c);
    }
}

// =============================================================== k_head
// 1 block: relu(pooled@lin1+b) -> LDS -> @lin2+b2 -> log_softmax -> out
__global__ __launch_bounds__(256) void k_head(const short* __restrict__ pooled,
                                              const short* __restrict__ Wp8,
                                              const short* __restrict__ Wp9,
                                              const float* __restrict__ b1h,
                                              const float* __restrict__ b2h,
                                              float* __restrict__ out) {
    __shared__ __align__(16) short Hl[128 * LSTRIDE];    // 34816 B
    __shared__ float Ll[128 * OUT_DIM];                  // 20480 B
    int tid = threadIdx.x, lane = tid & 63, w = tid >> 6;
    int m16 = lane & 15, quad = lane >> 4;

    // ---- mm1: wave w: rows (w>>1)*64, cols (w&1)*64
    {
        int nh = w & 1, mh = w >> 1, base = mh * 64;
        float pb[4];
#pragma unroll
        for (int nt = 0; nt < 4; nt++) pb[nt] = b1h[nh * 64 + nt * 16 + m16];
        v4f acc[4][4];
#pragma unroll
        for (int mt = 0; mt < 4; mt++)
#pragma unroll
            for (int nt = 0; nt < 4; nt++) acc[mt][nt] = {0.f, 0.f, 0.f, 0.f};
#pragma unroll
        for (int ks = 0; ks < 4; ks++) {
            v8s bfr[4];
#pragma unroll
            for (int nt = 0; nt < 4; nt++)
                bfr[nt] = ((const v8s*)Wp8)[(ks * 8 + nh * 4 + nt) * 64 + lane];
#pragma unroll
            for (int mt = 0; mt < 4; mt++) {
                v8s a = *(const v8s*)(pooled + (size_t)(base + mt * 16 + m16) * HID
                                      + ks * 32 + quad * 8);
#pragma unroll
                for (int nt = 0; nt < 4; nt++)
                    acc[mt][nt] = __builtin_amdgcn_mfma_f32_16x16x32_bf16(a, bfr[nt], acc[mt][nt], 0, 0, 0);
            }
        }
#pragma unroll
        for (int mt = 0; mt < 4; mt++)
#pragma unroll
            for (int r4 = 0; r4 < 4; r4++) {
                int row = base + mt * 16 + quad * 4 + r4;
#pragma unroll
                for (int nt = 0; nt < 4; nt++)
                    Hl[row * LSTRIDE + nh * 64 + nt * 16 + m16] =
                        f2bf(fmaxf(acc[mt][nt][r4] + pb[nt], 0.f));
            }
    }
    __syncthreads();

    // ---- mm2: wave w: rows w*32..+32, cols 0..47 (only <40 kept)
    {
        v4f acc[2][3];
#pragma unroll
        for (int mt = 0; mt < 2; mt++)
#pragma unroll
            for (int nt = 0; nt < 3; nt++) acc[mt][nt] = {0.f, 0.f, 0.f, 0.f};
#pragma unroll
        for (int ks = 0; ks < 4; ks++) {
            v8s bfr[3];
#pragma unroll
            for (int nt = 0; nt < 3; nt++)
                bfr[nt] = ((const v8s*)Wp9)[(ks * 8 + nt) * 64 + lane];
#pragma unroll
            for (int mt = 0; mt < 2; mt++) {
                v8s a = *(const v8s*)&Hl[(w * 32 + mt * 16 + m16) * LSTRIDE + ks * 32 + quad * 8];
#pragma unroll
                for (int nt = 0; nt < 3; nt++)
                    acc[mt][nt] = __builtin_amdgcn_mfma_f32_16x16x32_bf16(a, bfr[nt], acc[mt][nt], 0, 0, 0);
            }
        }
#pragma unroll
        for (int mt = 0; mt < 2; mt++)
#pragma unroll
            for (int r4 = 0; r4 < 4; r4++) {
                int row = w * 32 + mt * 16 + quad * 4 + r4;
#pragma unroll
                for (int nt = 0; nt < 3; nt++) {
                    int col = nt * 16 + m16;
                    if (col < OUT_DIM)
                        Ll[row * OUT_DIM + col] = acc[mt][nt][r4] + b2h[col];
                }
            }
    }
    __syncthreads();

    // ---- log_softmax per graph (32 graphs / wave)
    for (int g = w; g < N_GRAPHS; g += 4) {
        float a = (lane < OUT_DIM) ? Ll[g * OUT_DIM + lane] : -INFINITY;
        float v = a;
        for (int d = 32; d > 0; d >>= 1) v = fmaxf(v, __shfl_xor(v, d, 64));
        float ex = (lane < OUT_DIM) ? expf(a - v) : 0.0f;
        float s = ex;
        for (int d = 32; d > 0; d >>= 1) s += __shfl_xor(s, d, 64);
        if (lane < OUT_DIM) out[g * OUT_DIM + lane] = a - v - logf(s);
    }
}

// ----------------------------------------------------------------- launcher
extern "C" void kernel_launch(void* const* d_in, const int* in_sizes, int n_in,
                              void* d_out, int out_size, void* d_ws, size_t ws_size,
                              hipStream_t stream) {
    const float* x       = (const float*)d_in[0];
    const int*   edge    = (const int*)d_in[1];
    const int*   batch   = (const int*)d_in[2];
    const float* W1s     = (const float*)d_in[3];
    const float* b1s     = (const float*)d_in[4];
    const float* W2s     = (const float*)d_in[5];
    const float* b2s     = (const float*)d_in[6];
    const float* gammas  = (const float*)d_in[7];
    const float* betas   = (const float*)d_in[8];
    const float* bn_m    = (const float*)d_in[9];
    const float* bn_v    = (const float*)d_in[10];
    const float* eps_arr = (const float*)d_in[11];
    const float* lin1_W  = (const float*)d_in[12];
    const float* lin1_b  = (const float*)d_in[13];
    const float* lin2_W  = (const float*)d_in[14];
    const float* lin2_b  = (const float*)d_in[15];

    const int* src = edge;
    const int* dst = edge + N_EDGES;

    // workspace layout (≈ 32.6 MB)
    short* bufA    = (short*)d_ws;                        // 50000*128 bf16
    short* bufB    = bufA + (size_t)N_NODES * HID;
    short* Wp      = bufB + (size_t)N_NODES * HID;        // 10 slots * 16384 bf16
    short* pooled  = Wp + 10 * 16384;                     // 128*128 bf16
    int*   cursor  = (int*)(pooled + N_GRAPHS * HID);     // 50000 (degree after fill)
    unsigned short* csr = (unsigned short*)(cursor + N_NODES);   // 50000*CAP ushort

    // ---- zero cursor, then fused pre-pass (fill + x2b + weight prep)
    (void)hipMemsetAsync(cursor, 0, N_NODES * sizeof(int), stream);
    k_pre<<<3917, 256, 0, stream>>>(x, (unsigned*)bufA, src, dst, cursor, csr,
                                    W1s, W2s, lin1_W, lin2_W, Wp);

    // ---- fused GIN layers
    const int mlpBlocks = (N_NODES + TROWS - 1) / TROWS;   // 1563
    short* in   = bufA;
    short* outb = bufB;
    for (int l = 0; l < N_LAYERS; l++) {
        k_mlp<<<mlpBlocks, 256, 0, stream>>>(in, csr, cursor,
                                             Wp + (size_t)l * 16384,
                                             Wp + (size_t)(4 + l) * 16384,
                                             b1s + l * HID, b2s + l * HID,
                                             gammas + l * HID, betas + l * HID,
                                             bn_m + l * HID, bn_v + l * HID,
                                             eps_arr, l, outb, N_NODES);
        short* tmp = in; in = outb; outb = tmp;
    }

    // ---- pool + head
    k_pool<<<N_GRAPHS, 256, 0, stream>>>(in, batch, pooled);
    k_head<<<1, 256, 0, stream>>>(pooled, Wp + (size_t)8 * 16384, Wp + (size_t)9 * 16384,
                                  lin1_b, lin2_b, (float*)d_out);
}